// Round 1
// baseline (3580.845 us; speedup 1.0000x reference)
//
#include <hip/hip_runtime.h>
#include <stdint.h>
#include <stddef.h>

// Problem dims
#define B_ 1024
#define S_ 128
#define D_ 256
#define H_ 2048
#define O_ 10
#define V_ 10

// Step-GEMM tile config: C[1024 x 2048] = Hin[1024 x 2048(K)] * W[2048(N) x 2048(K)]^T
#define BM 64
#define BN 128
#define BK 64

typedef unsigned short u16;
typedef short v8s __attribute__((ext_vector_type(8)));    // 8 x bf16 (4 VGPRs) MFMA A/B frag
typedef float v4f __attribute__((ext_vector_type(4)));    // 4 x f32 MFMA C/D frag
typedef u16 u16x4 __attribute__((ext_vector_type(4)));

__device__ __forceinline__ u16 f2bf(float f) {
  unsigned int u = __float_as_uint(f);
  u += 0x7FFFu + ((u >> 16) & 1u);   // RNE
  return (u16)(u >> 16);
}
__device__ __forceinline__ float bf2f(u16 h) {
  return __uint_as_float(((unsigned int)h) << 16);
}
__device__ __forceinline__ float fast_tanh(float x) {
  // tanh(x) = 1 - 2/(exp(2x)+1); exact at saturation, ~1e-6 rel err
  float e = __expf(2.0f * x);
  return 1.0f - 2.0f / (e + 1.0f);
}
__device__ __forceinline__ void gl2lds16(const void* g, void* l) {
  __builtin_amdgcn_global_load_lds(
      (const __attribute__((address_space(1))) uint32_t*)g,
      (__attribute__((address_space(3))) uint32_t*)l, 16, 0, 0);
}

// ---------------- Txh[v][h] = b_hx[h] + sum_d embed[v][d]*W_hx[h][d] ----------------
__global__ __launch_bounds__(256) void make_table(const float* __restrict__ embed,
                                                  const float* __restrict__ W_hx,
                                                  const float* __restrict__ b_hx,
                                                  float* __restrict__ Txh) {
  int idx = blockIdx.x * 256 + threadIdx.x;   // 10*2048 = 20480
  int v = idx >> 11, h = idx & 2047;
  const float4* e4 = (const float4*)(embed + v * D_);
  const float4* w4 = (const float4*)(W_hx + (size_t)h * D_);
  float s = b_hx[h];
#pragma unroll 4
  for (int d = 0; d < D_ / 4; ++d) {
    float4 a = e4[d], b = w4[d];
    s = fmaf(a.x, b.x, s); s = fmaf(a.y, b.y, s);
    s = fmaf(a.z, b.z, s); s = fmaf(a.w, b.w, s);
  }
  Txh[idx] = s;
}

// ---------------- W_hh (f32) -> bf16, same [N][K] layout ----------------
__global__ __launch_bounds__(256) void conv_w(const float* __restrict__ W,
                                              u16* __restrict__ Wb) {
  int i = blockIdx.x * 256 + threadIdx.x;     // over 4M/4 = 1M float4
  float4 w = ((const float4*)W)[i];
  u16x4 o = { f2bf(w.x), f2bf(w.y), f2bf(w.z), f2bf(w.w) };
  ((u16x4*)Wb)[i] = o;
}

// ---------------- h0[b][j] = tanh(Txh[x[b,0]][j])  (no b_hh at step 0) ----------------
__global__ __launch_bounds__(256) void init_h0(const float* __restrict__ Txh,
                                               const int* __restrict__ x,
                                               u16* __restrict__ H0) {
  int idx = blockIdx.x * 256 + threadIdx.x;   // 1024*2048 = 2M
  int b = idx >> 11, j = idx & 2047;
  int xv = x[b * S_];
  H0[idx] = f2bf(fast_tanh(Txh[xv * H_ + j]));
}

// ---------------- one recurrence step:
// Hout[b][n] = tanh( sum_k Hin[b][k]*Wb[n][k] + Txh[x[b,t]][n] + b_hh[n] )
// grid (N/BN=16, M/BM=16), 256 threads (4 waves), wave computes 32x64.
// LDS tiles stored as [row][8 chunks of 8 bf16], chunk XOR-swizzled: slot(m,c)=m*8+(c^(m&7)).
__global__ __launch_bounds__(256) void rnn_step(const u16* __restrict__ Hin,
                                                const u16* __restrict__ Wb,
                                                const float* __restrict__ Txh,
                                                const int* __restrict__ x,
                                                const float* __restrict__ b_hh,
                                                u16* __restrict__ Hout,
                                                int t) {
  __shared__ __align__(16) u16 As[BM * BK];   // 8 KB
  __shared__ __align__(16) u16 Bs[BN * BK];   // 16 KB

  const int tid = threadIdx.x;
  const int bm = blockIdx.y * BM;
  const int bn = blockIdx.x * BN;
  const int w = tid >> 6, l = tid & 63;
  const int wr = w >> 1, wc = w & 1;          // wave tile origin: (wr*32, wc*64)
  const int lane16 = l & 15, quad = l >> 4;

  v4f acc[2][4];
#pragma unroll
  for (int i = 0; i < 2; ++i)
#pragma unroll
    for (int j = 0; j < 4; ++j) acc[i][j] = (v4f){0.f, 0.f, 0.f, 0.f};

  for (int kt = 0; kt < H_ / BK; ++kt) {
    const int kbase = kt * BK;
    // stage A: 64 rows * 8 chunks = 512 slots, 2 issues of 256 threads
#pragma unroll
    for (int i = 0; i < 2; ++i) {
      int s = i * 256 + tid;
      int m = s >> 3;
      int cg = (s & 7) ^ (m & 7);             // swizzle applied on the global side
      const u16* g = Hin + (size_t)(bm + m) * H_ + kbase + cg * 8;
      u16* lp = &As[(i * 256 + (w << 6)) * 8];  // wave-uniform base; lane lands at +l*16B
      gl2lds16(g, lp);
    }
    // stage B: 128 rows * 8 chunks = 1024 slots, 4 issues
#pragma unroll
    for (int i = 0; i < 4; ++i) {
      int s = i * 256 + tid;
      int n = s >> 3;
      int cg = (s & 7) ^ (n & 7);
      const u16* g = Wb + (size_t)(bn + n) * H_ + kbase + cg * 8;
      u16* lp = &Bs[(i * 256 + (w << 6)) * 8];
      gl2lds16(g, lp);
    }
    __syncthreads();   // drains vmcnt (global_load_lds) + barrier

#pragma unroll
    for (int kc = 0; kc < 2; ++kc) {
      int cc = kc * 4 + quad;                 // k-chunk index within row (k = cc*8 .. +7)
      v8s a[2], bf[4];
#pragma unroll
      for (int i = 0; i < 2; ++i) {
        int m = wr * 32 + i * 16 + lane16;
        a[i] = *(const v8s*)&As[(m * 8 + (cc ^ (m & 7))) * 8];
      }
#pragma unroll
      for (int j = 0; j < 4; ++j) {
        int n = wc * 64 + j * 16 + lane16;
        bf[j] = *(const v8s*)&Bs[(n * 8 + (cc ^ (n & 7))) * 8];
      }
#pragma unroll
      for (int i = 0; i < 2; ++i)
#pragma unroll
        for (int j = 0; j < 4; ++j)
          acc[i][j] = __builtin_amdgcn_mfma_f32_16x16x32_bf16(a[i], bf[j], acc[i][j], 0, 0, 0);
    }
    __syncthreads();   // all waves done reading LDS before next stage overwrites
  }

  // epilogue: C/D layout col=lane&15, row=quad*4+reg  [m89-verified]
  const int colb = bn + wc * 64 + lane16;
  float bh[4];
#pragma unroll
  for (int j = 0; j < 4; ++j) bh[j] = b_hh[colb + j * 16];
#pragma unroll
  for (int i = 0; i < 2; ++i) {
#pragma unroll
    for (int r = 0; r < 4; ++r) {
      int row = bm + wr * 32 + i * 16 + quad * 4 + r;
      const float* trow = Txh + x[row * S_ + t] * H_;
      u16* orow = Hout + (size_t)row * H_;
#pragma unroll
      for (int j = 0; j < 4; ++j) {
        int col = colb + j * 16;
        float v = acc[i][j][r] + trow[col] + bh[j];
        orow[col] = f2bf(fast_tanh(v));
      }
    }
  }
}

// ---------------- o = hT @ W_oh^T + b_oh ; softmax over 10 ----------------
__global__ __launch_bounds__(256) void out_softmax(const u16* __restrict__ Hf,
                                                   const float* __restrict__ W_oh,
                                                   const float* __restrict__ b_oh,
                                                   float* __restrict__ out) {
  int b = blockIdx.x, tid = threadIdx.x;
  float hv[8];
  const u16* hr = Hf + (size_t)b * H_ + tid * 8;
#pragma unroll
  for (int u = 0; u < 8; ++u) hv[u] = bf2f(hr[u]);
  float acc[O_];
#pragma unroll
  for (int i = 0; i < O_; ++i) {
    const float* wr = W_oh + (size_t)i * H_ + tid * 8;
    float s = 0.f;
#pragma unroll
    for (int u = 0; u < 8; ++u) s = fmaf(hv[u], wr[u], s);
    acc[i] = s;
  }
#pragma unroll
  for (int off = 32; off > 0; off >>= 1)
#pragma unroll
    for (int i = 0; i < O_; ++i) acc[i] += __shfl_down(acc[i], off);
  __shared__ float red[4][O_];
  if ((tid & 63) == 0)
#pragma unroll
    for (int i = 0; i < O_; ++i) red[tid >> 6][i] = acc[i];
  __syncthreads();
  if (tid == 0) {
    float o[O_], mx = -1e30f;
#pragma unroll
    for (int i = 0; i < O_; ++i) {
      o[i] = red[0][i] + red[1][i] + red[2][i] + red[3][i] + b_oh[i];
      mx = fmaxf(mx, o[i]);
    }
    float se = 0.f;
#pragma unroll
    for (int i = 0; i < O_; ++i) { o[i] = __expf(o[i] - mx); se += o[i]; }
    float inv = 1.f / se;
#pragma unroll
    for (int i = 0; i < O_; ++i) out[b * O_ + i] = o[i] * inv;
  }
}

extern "C" void kernel_launch(void* const* d_in, const int* in_sizes, int n_in,
                              void* d_out, int out_size, void* d_ws, size_t ws_size,
                              hipStream_t stream) {
  const int*   x     = (const int*)  d_in[0];
  const float* embed = (const float*)d_in[1];
  const float* W_hx  = (const float*)d_in[2];
  const float* b_hx  = (const float*)d_in[3];
  const float* W_hh  = (const float*)d_in[4];
  const float* b_hh  = (const float*)d_in[5];
  const float* W_oh  = (const float*)d_in[6];
  const float* b_oh  = (const float*)d_in[7];
  float* out = (float*)d_out;

  // workspace layout: Txh 80KB | Wb 8MB | Ha 4MB | Hb 4MB  (~16.1 MB)
  char* ws = (char*)d_ws;
  float* Txh = (float*)ws;
  u16* Wb = (u16*)(ws + (80 << 10));
  u16* Ha = (u16*)(ws + (80 << 10) + (8 << 20));
  u16* Hb = (u16*)(ws + (80 << 10) + (12 << 20));

  make_table<<<80, 256, 0, stream>>>(embed, W_hx, b_hx, Txh);
  conv_w<<<4096, 256, 0, stream>>>(W_hh, Wb);
  init_h0<<<8192, 256, 0, stream>>>(Txh, x, Ha);

  dim3 sg(H_ / BN, B_ / BM);   // (16,16)
  for (int t = 1; t < S_; ++t) {
    const u16* hin = (t & 1) ? Ha : Hb;
    u16* hout = (t & 1) ? Hb : Ha;
    rnn_step<<<sg, 256, 0, stream>>>(hin, Wb, Txh, x, b_hh, hout, t);
  }
  // t=127 (odd) wrote Hb
  out_softmax<<<B_, 256, 0, stream>>>(Hb, W_oh, b_oh, out);
}

// Round 2
// 2352.474 us; speedup vs baseline: 1.5222x; 1.5222x over previous
//
#include <hip/hip_runtime.h>
#include <stdint.h>
#include <stddef.h>

// Problem dims
#define B_ 1024
#define S_ 128
#define D_ 256
#define H_ 2048
#define O_ 10
#define V_ 10

// Step-GEMM tile config: C[1024 x 2048] = Hin[1024 x 2048(K)] * W[2048(N) x 2048(K)]^T
// BM=BN=64, BK=128, grid 512 (2 WG/CU), double-buffered LDS (64 KB/WG).
#define BM 64
#define BN 64
#define BK 128
#define NKT (H_ / BK)   // 16 K-iterations

typedef unsigned short u16;
typedef short v8s __attribute__((ext_vector_type(8)));    // 8 x bf16 (4 VGPRs) MFMA A/B frag
typedef float v4f __attribute__((ext_vector_type(4)));    // 4 x f32 MFMA C/D frag
typedef u16 u16x4 __attribute__((ext_vector_type(4)));

__device__ __forceinline__ u16 f2bf(float f) {
  unsigned int u = __float_as_uint(f);
  u += 0x7FFFu + ((u >> 16) & 1u);   // RNE
  return (u16)(u >> 16);
}
__device__ __forceinline__ float bf2f(u16 h) {
  return __uint_as_float(((unsigned int)h) << 16);
}
__device__ __forceinline__ float fast_tanh(float x) {
  float e = __expf(2.0f * x);
  return 1.0f - 2.0f / (e + 1.0f);
}
__device__ __forceinline__ void gl2lds16(const void* g, void* l) {
  __builtin_amdgcn_global_load_lds(
      (const __attribute__((address_space(1))) uint32_t*)g,
      (__attribute__((address_space(3))) uint32_t*)l, 16, 0, 0);
}

// ---------------- Txh[v][h] = b_hx[h] + sum_d embed[v][d]*W_hx[h][d] ----------------
__global__ __launch_bounds__(256) void make_table(const float* __restrict__ embed,
                                                  const float* __restrict__ W_hx,
                                                  const float* __restrict__ b_hx,
                                                  float* __restrict__ Txh) {
  int idx = blockIdx.x * 256 + threadIdx.x;   // 10*2048 = 20480
  int v = idx >> 11, h = idx & 2047;
  const float4* e4 = (const float4*)(embed + v * D_);
  const float4* w4 = (const float4*)(W_hx + (size_t)h * D_);
  float s = b_hx[h];
#pragma unroll 4
  for (int d = 0; d < D_ / 4; ++d) {
    float4 a = e4[d], b = w4[d];
    s = fmaf(a.x, b.x, s); s = fmaf(a.y, b.y, s);
    s = fmaf(a.z, b.z, s); s = fmaf(a.w, b.w, s);
  }
  Txh[idx] = s;
}

// ---------------- W_hh (f32) -> bf16, same [N][K] layout ----------------
__global__ __launch_bounds__(256) void conv_w(const float* __restrict__ W,
                                              u16* __restrict__ Wb) {
  int i = blockIdx.x * 256 + threadIdx.x;     // over 4M/4 = 1M float4
  float4 w = ((const float4*)W)[i];
  u16x4 o = { f2bf(w.x), f2bf(w.y), f2bf(w.z), f2bf(w.w) };
  ((u16x4*)Wb)[i] = o;
}

// ---------------- h0[b][j] = tanh(Txh[x[b,0]][j])  (no b_hh at step 0) ----------------
__global__ __launch_bounds__(256) void init_h0(const float* __restrict__ Txh,
                                               const int* __restrict__ x,
                                               u16* __restrict__ H0) {
  int idx = blockIdx.x * 256 + threadIdx.x;   // 1024*2048 = 2M
  int b = idx >> 11, j = idx & 2047;
  int xv = x[b * S_];
  H0[idx] = f2bf(fast_tanh(Txh[xv * H_ + j]));
}

// ---------------- one recurrence step ----------------
// Hout[b][n] = tanh( sum_k Hin[b][k]*Wb[n][k] + Txh[x[b,t]][n] + b_hh[n] )
// 512 WGs (2/CU), 256 threads (4 waves as 2x2 of 32x32), double-buffered LDS.
// LDS tiles: [row][16 chunks of 8 bf16], chunk XOR-swizzled: slot(m,c) = m*16 + (c^(m&15)).
// XCD swizzle: bid&7 -> xcd; each xcd owns 4 bn-groups (1 MB W slice, L2-resident).

__device__ __forceinline__ void stage_tiles(const u16* __restrict__ Hin,
                                            const u16* __restrict__ Wb,
                                            u16* __restrict__ As, u16* __restrict__ Bs,
                                            int bm, int bn, int kbase, int tid, int w) {
  // A: 64 rows * 16 chunks = 1024 slots of 16B; 4 issues of 256 threads
#pragma unroll
  for (int i = 0; i < 4; ++i) {
    int s = i * 256 + tid;
    int m = s >> 4;
    int cg = (s & 15) ^ (m & 15);             // swizzle applied on the global side
    const u16* g = Hin + (size_t)(bm + m) * H_ + kbase + cg * 8;
    u16* lp = As + (size_t)(i * 256 + (w << 6)) * 8;  // wave-uniform base; lane lands at +l*16B
    gl2lds16(g, lp);
  }
  // B: 64 rows * 16 chunks = 1024 slots; 4 issues
#pragma unroll
  for (int i = 0; i < 4; ++i) {
    int s = i * 256 + tid;
    int n = s >> 4;
    int cg = (s & 15) ^ (n & 15);
    const u16* g = Wb + (size_t)(bn + n) * H_ + kbase + cg * 8;
    u16* lp = Bs + (size_t)(i * 256 + (w << 6)) * 8;
    gl2lds16(g, lp);
  }
}

__global__ __launch_bounds__(256, 2) void rnn_step(const u16* __restrict__ Hin,
                                                   const u16* __restrict__ Wb,
                                                   const float* __restrict__ Txh,
                                                   const int* __restrict__ x,
                                                   const float* __restrict__ b_hh,
                                                   u16* __restrict__ Hout,
                                                   int t) {
  __shared__ __align__(16) u16 As[2][BM * BK];   // 2 x 16 KB
  __shared__ __align__(16) u16 Bs[2][BN * BK];   // 2 x 16 KB

  const int tid = threadIdx.x;
  const int bid = blockIdx.x;
  // XCD-aware swizzle: xcd = bid&7 owns bn-groups {4*xcd .. 4*xcd+3}
  const int xcd = bid & 7;
  const int sl = bid >> 3;                     // 0..63
  const int bn = (xcd * 4 + (sl & 3)) * BN;    // 32 bn-groups
  const int bm = (sl >> 2) * BM;               // 16 bm-groups

  const int w = tid >> 6, l = tid & 63;
  const int wr = w >> 1, wc = w & 1;           // wave tile origin: (wr*32, wc*32)
  const int lane16 = l & 15, quad = l >> 4;

  v4f acc[2][2];
#pragma unroll
  for (int i = 0; i < 2; ++i)
#pragma unroll
    for (int j = 0; j < 2; ++j) acc[i][j] = (v4f){0.f, 0.f, 0.f, 0.f};

  stage_tiles(Hin, Wb, As[0], Bs[0], bm, bn, 0, tid, w);
  __syncthreads();

  for (int kt = 0; kt < NKT; ++kt) {
    const int cur = kt & 1;
    if (kt + 1 < NKT)
      stage_tiles(Hin, Wb, As[cur ^ 1], Bs[cur ^ 1], bm, bn, (kt + 1) * BK, tid, w);

#pragma unroll
    for (int kc = 0; kc < 4; ++kc) {
      const int cc = kc * 4 + quad;            // k-chunk index within row
      v8s a[2], bf[2];
#pragma unroll
      for (int i = 0; i < 2; ++i) {
        int m = wr * 32 + i * 16 + lane16;     // m&15 == lane16 -> conflict-free
        a[i] = *(const v8s*)&As[cur][(m * 16 + (cc ^ lane16)) * 8];
      }
#pragma unroll
      for (int j = 0; j < 2; ++j) {
        int n = wc * 32 + j * 16 + lane16;
        bf[j] = *(const v8s*)&Bs[cur][(n * 16 + (cc ^ lane16)) * 8];
      }
#pragma unroll
      for (int i = 0; i < 2; ++i)
#pragma unroll
        for (int j = 0; j < 2; ++j)
          acc[i][j] = __builtin_amdgcn_mfma_f32_16x16x32_bf16(a[i], bf[j], acc[i][j], 0, 0, 0);
    }
    __syncthreads();   // drains the kt+1 loads (already had a full compute phase in flight)
  }

  // epilogue: C/D layout col=lane&15, row=quad*4+reg  [m89-verified]
  const int colb = bn + wc * 32 + lane16;
  float bh[2];
#pragma unroll
  for (int j = 0; j < 2; ++j) bh[j] = b_hh[colb + j * 16];
#pragma unroll
  for (int i = 0; i < 2; ++i) {
#pragma unroll
    for (int r = 0; r < 4; ++r) {
      int row = bm + wr * 32 + i * 16 + quad * 4 + r;
      const float* trow = Txh + x[row * S_ + t] * H_;
      u16* orow = Hout + (size_t)row * H_;
#pragma unroll
      for (int j = 0; j < 2; ++j) {
        int col = colb + j * 16;
        float v = acc[i][j][r] + trow[col] + bh[j];
        orow[col] = f2bf(fast_tanh(v));
      }
    }
  }
}

// ---------------- o = hT @ W_oh^T + b_oh ; softmax over 10 ----------------
__global__ __launch_bounds__(256) void out_softmax(const u16* __restrict__ Hf,
                                                   const float* __restrict__ W_oh,
                                                   const float* __restrict__ b_oh,
                                                   float* __restrict__ out) {
  int b = blockIdx.x, tid = threadIdx.x;
  float hv[8];
  const u16* hr = Hf + (size_t)b * H_ + tid * 8;
#pragma unroll
  for (int u = 0; u < 8; ++u) hv[u] = bf2f(hr[u]);
  float acc[O_];
#pragma unroll
  for (int i = 0; i < O_; ++i) {
    const float* wr = W_oh + (size_t)i * H_ + tid * 8;
    float s = 0.f;
#pragma unroll
    for (int u = 0; u < 8; ++u) s = fmaf(hv[u], wr[u], s);
    acc[i] = s;
  }
#pragma unroll
  for (int off = 32; off > 0; off >>= 1)
#pragma unroll
    for (int i = 0; i < O_; ++i) acc[i] += __shfl_down(acc[i], off);
  __shared__ float red[4][O_];
  if ((tid & 63) == 0)
#pragma unroll
    for (int i = 0; i < O_; ++i) red[tid >> 6][i] = acc[i];
  __syncthreads();
  if (tid == 0) {
    float o[O_], mx = -1e30f;
#pragma unroll
    for (int i = 0; i < O_; ++i) {
      o[i] = red[0][i] + red[1][i] + red[2][i] + red[3][i] + b_oh[i];
      mx = fmaxf(mx, o[i]);
    }
    float se = 0.f;
#pragma unroll
    for (int i = 0; i < O_; ++i) { o[i] = __expf(o[i] - mx); se += o[i]; }
    float inv = 1.f / se;
#pragma unroll
    for (int i = 0; i < O_; ++i) out[b * O_ + i] = o[i] * inv;
  }
}

extern "C" void kernel_launch(void* const* d_in, const int* in_sizes, int n_in,
                              void* d_out, int out_size, void* d_ws, size_t ws_size,
                              hipStream_t stream) {
  const int*   x     = (const int*)  d_in[0];
  const float* embed = (const float*)d_in[1];
  const float* W_hx  = (const float*)d_in[2];
  const float* b_hx  = (const float*)d_in[3];
  const float* W_hh  = (const float*)d_in[4];
  const float* b_hh  = (const float*)d_in[5];
  const float* W_oh  = (const float*)d_in[6];
  const float* b_oh  = (const float*)d_in[7];
  float* out = (float*)d_out;

  // workspace layout: Txh 80KB | Wb 8MB | Ha 4MB | Hb 4MB  (~16.1 MB)
  char* ws = (char*)d_ws;
  float* Txh = (float*)ws;
  u16* Wb = (u16*)(ws + (80 << 10));
  u16* Ha = (u16*)(ws + (80 << 10) + (8 << 20));
  u16* Hb = (u16*)(ws + (80 << 10) + (12 << 20));

  make_table<<<80, 256, 0, stream>>>(embed, W_hx, b_hx, Txh);
  conv_w<<<4096, 256, 0, stream>>>(W_hh, Wb);
  init_h0<<<8192, 256, 0, stream>>>(Txh, x, Ha);

  for (int t = 1; t < S_; ++t) {
    const u16* hin = (t & 1) ? Ha : Hb;
    u16* hout = (t & 1) ? Hb : Ha;
    rnn_step<<<512, 256, 0, stream>>>(hin, Wb, Txh, x, b_hh, hout, t);
  }
  // t=127 (odd) wrote Hb
  out_softmax<<<B_, 256, 0, stream>>>(Hb, W_oh, b_oh, out);
}

// Round 3
// 2301.015 us; speedup vs baseline: 1.5562x; 1.0224x over previous
//
#include <hip/hip_runtime.h>
#include <stdint.h>
#include <stddef.h>

// Problem dims
#define B_ 1024
#define S_ 128
#define D_ 256
#define H_ 2048
#define O_ 10
#define V_ 10

// Step-GEMM tile config: C[1024 x 2048] = Hin[1024 x 2048(K)] * W[2048(N) x 2048(K)]^T
// BM=BN=64, BK=128, grid 512 (2 WG/CU), double-buffered LDS (64 KB/WG).
#define BM 64
#define BN 64
#define BK 128
#define NKT (H_ / BK)   // 16 K-iterations

typedef unsigned short u16;
typedef short v8s __attribute__((ext_vector_type(8)));    // 8 x bf16 (4 VGPRs) MFMA A/B frag
typedef float v4f __attribute__((ext_vector_type(4)));    // 4 x f32 MFMA C/D frag
typedef u16 u16x4 __attribute__((ext_vector_type(4)));

__device__ __forceinline__ u16 f2bf(float f) {
  unsigned int u = __float_as_uint(f);
  u += 0x7FFFu + ((u >> 16) & 1u);   // RNE
  return (u16)(u >> 16);
}
__device__ __forceinline__ float bf2f(u16 h) {
  return __uint_as_float(((unsigned int)h) << 16);
}
__device__ __forceinline__ float fast_tanh(float x) {
  float e = __expf(2.0f * x);
  return 1.0f - 2.0f / (e + 1.0f);
}
__device__ __forceinline__ void gl2lds16(const void* g, void* l) {
  __builtin_amdgcn_global_load_lds(
      (const __attribute__((address_space(1))) uint32_t*)g,
      (__attribute__((address_space(3))) uint32_t*)l, 16, 0, 0);
}

// ---------------- Txh[v][h] = b_hx[h] + sum_d embed[v][d]*W_hx[h][d] ----------------
__global__ __launch_bounds__(256) void make_table(const float* __restrict__ embed,
                                                  const float* __restrict__ W_hx,
                                                  const float* __restrict__ b_hx,
                                                  float* __restrict__ Txh) {
  int idx = blockIdx.x * 256 + threadIdx.x;   // 10*2048 = 20480
  int v = idx >> 11, h = idx & 2047;
  const float4* e4 = (const float4*)(embed + v * D_);
  const float4* w4 = (const float4*)(W_hx + (size_t)h * D_);
  float s = b_hx[h];
#pragma unroll 4
  for (int d = 0; d < D_ / 4; ++d) {
    float4 a = e4[d], b = w4[d];
    s = fmaf(a.x, b.x, s); s = fmaf(a.y, b.y, s);
    s = fmaf(a.z, b.z, s); s = fmaf(a.w, b.w, s);
  }
  Txh[idx] = s;
}

// ---------------- W_hh (f32) -> bf16, same [N][K] layout ----------------
__global__ __launch_bounds__(256) void conv_w(const float* __restrict__ W,
                                              u16* __restrict__ Wb) {
  int i = blockIdx.x * 256 + threadIdx.x;     // over 4M/4 = 1M float4
  float4 w = ((const float4*)W)[i];
  u16x4 o = { f2bf(w.x), f2bf(w.y), f2bf(w.z), f2bf(w.w) };
  ((u16x4*)Wb)[i] = o;
}

// ---------------- h0[b][j] = tanh(Txh[x[b,0]][j])  (no b_hh at step 0) ----------------
__global__ __launch_bounds__(256) void init_h0(const float* __restrict__ Txh,
                                               const int* __restrict__ x,
                                               u16* __restrict__ H0) {
  int idx = blockIdx.x * 256 + threadIdx.x;   // 1024*2048 = 2M
  int b = idx >> 11, j = idx & 2047;
  int xv = x[b * S_];
  H0[idx] = f2bf(fast_tanh(Txh[xv * H_ + j]));
}

// ---------------- one recurrence step ----------------
// Hout[b][n] = tanh( sum_k Hin[b][k]*Wb[n][k] + Txh[x[b,t]][n] + b_hh[n] )
// 512 WGs (2/CU), 256 threads (4 waves as 2x2 of 32x32), double-buffered LDS.
// LDS tiles: [row][16 chunks of 8 bf16], chunk XOR-swizzled: slot(m,c) = m*16 + (c^(m&15)).
//
// XCD swizzle (round-3 fix): 2-D per-XCD block. XCD grid is 2(rows)x4(cols);
// each XCD owns 8 bm-groups x 8 bn-groups -> per-XCD L2 footprint
// A 512 rows (2 MB) + W 512 rows (2 MB) = 4 MB = L2 capacity, and the W slice
// is step-invariant (L2-resident across all 127 steps). Round-2's mapping gave
// every XCD ALL 16 bm-groups (A 4 MB + W 1 MB = 5 MB > L2) -> L3 thrash.

__device__ __forceinline__ void stage_tiles(const u16* __restrict__ Hin,
                                            const u16* __restrict__ Wb,
                                            u16* __restrict__ As, u16* __restrict__ Bs,
                                            int bm, int bn, int kbase, int tid, int w) {
  // A: 64 rows * 16 chunks = 1024 slots of 16B; 4 issues of 256 threads
#pragma unroll
  for (int i = 0; i < 4; ++i) {
    int s = i * 256 + tid;
    int m = s >> 4;
    int cg = (s & 15) ^ (m & 15);             // swizzle applied on the global side
    const u16* g = Hin + (size_t)(bm + m) * H_ + kbase + cg * 8;
    u16* lp = As + (size_t)(i * 256 + (w << 6)) * 8;  // wave-uniform base; lane lands at +l*16B
    gl2lds16(g, lp);
  }
  // B: 64 rows * 16 chunks = 1024 slots; 4 issues
#pragma unroll
  for (int i = 0; i < 4; ++i) {
    int s = i * 256 + tid;
    int n = s >> 4;
    int cg = (s & 15) ^ (n & 15);
    const u16* g = Wb + (size_t)(bn + n) * H_ + kbase + cg * 8;
    u16* lp = Bs + (size_t)(i * 256 + (w << 6)) * 8;
    gl2lds16(g, lp);
  }
}

__global__ __launch_bounds__(256, 2) void rnn_step(const u16* __restrict__ Hin,
                                                   const u16* __restrict__ Wb,
                                                   const float* __restrict__ Txh,
                                                   const int* __restrict__ x,
                                                   const float* __restrict__ b_hh,
                                                   u16* __restrict__ Hout,
                                                   int t) {
  __shared__ __align__(16) u16 As[2][BM * BK];   // 2 x 16 KB
  __shared__ __align__(16) u16 Bs[2][BN * BK];   // 2 x 16 KB

  const int tid = threadIdx.x;
  const int bid = blockIdx.x;
  // 2-D XCD-aware swizzle (see header comment)
  const int xcd = bid & 7;
  const int sl  = bid >> 3;                    // 0..63 within XCD
  const int xr = xcd >> 2, xc = xcd & 3;       // XCD grid 2x4
  const int bm = (xr * 8 + (sl >> 3)) * BM;    // 16 bm-groups
  const int bn = (xc * 8 + (sl & 7)) * BN;     // 32 bn-groups

  const int w = tid >> 6, l = tid & 63;
  const int wr = w >> 1, wc = w & 1;           // wave tile origin: (wr*32, wc*32)
  const int lane16 = l & 15, quad = l >> 4;

  v4f acc[2][2];
#pragma unroll
  for (int i = 0; i < 2; ++i)
#pragma unroll
    for (int j = 0; j < 2; ++j) acc[i][j] = (v4f){0.f, 0.f, 0.f, 0.f};

  stage_tiles(Hin, Wb, As[0], Bs[0], bm, bn, 0, tid, w);
  __syncthreads();

  for (int kt = 0; kt < NKT; ++kt) {
    const int cur = kt & 1;
    if (kt + 1 < NKT)
      stage_tiles(Hin, Wb, As[cur ^ 1], Bs[cur ^ 1], bm, bn, (kt + 1) * BK, tid, w);

#pragma unroll
    for (int kc = 0; kc < 4; ++kc) {
      const int cc = kc * 4 + quad;            // k-chunk index within row
      v8s a[2], bf[2];
#pragma unroll
      for (int i = 0; i < 2; ++i) {
        int m = wr * 32 + i * 16 + lane16;     // m&15 == lane16 -> conflict-free
        a[i] = *(const v8s*)&As[cur][(m * 16 + (cc ^ lane16)) * 8];
      }
#pragma unroll
      for (int j = 0; j < 2; ++j) {
        int n = wc * 32 + j * 16 + lane16;
        bf[j] = *(const v8s*)&Bs[cur][(n * 16 + (cc ^ lane16)) * 8];
      }
#pragma unroll
      for (int i = 0; i < 2; ++i)
#pragma unroll
        for (int j = 0; j < 2; ++j)
          acc[i][j] = __builtin_amdgcn_mfma_f32_16x16x32_bf16(a[i], bf[j], acc[i][j], 0, 0, 0);
    }
    __syncthreads();   // drains the kt+1 loads (already had a full compute phase in flight)
  }

  // epilogue: C/D layout col=lane&15, row=quad*4+reg  [m89-verified]
  const int colb = bn + wc * 32 + lane16;
  float bh[2];
#pragma unroll
  for (int j = 0; j < 2; ++j) bh[j] = b_hh[colb + j * 16];
#pragma unroll
  for (int i = 0; i < 2; ++i) {
#pragma unroll
    for (int r = 0; r < 4; ++r) {
      int row = bm + wr * 32 + i * 16 + quad * 4 + r;
      const float* trow = Txh + x[row * S_ + t] * H_;
      u16* orow = Hout + (size_t)row * H_;
#pragma unroll
      for (int j = 0; j < 2; ++j) {
        int col = colb + j * 16;
        float v = acc[i][j][r] + trow[col] + bh[j];
        orow[col] = f2bf(fast_tanh(v));
      }
    }
  }
}

// ---------------- o = hT @ W_oh^T + b_oh ; softmax over 10 ----------------
__global__ __launch_bounds__(256) void out_softmax(const u16* __restrict__ Hf,
                                                   const float* __restrict__ W_oh,
                                                   const float* __restrict__ b_oh,
                                                   float* __restrict__ out) {
  int b = blockIdx.x, tid = threadIdx.x;
  float hv[8];
  const u16* hr = Hf + (size_t)b * H_ + tid * 8;
#pragma unroll
  for (int u = 0; u < 8; ++u) hv[u] = bf2f(hr[u]);
  float acc[O_];
#pragma unroll
  for (int i = 0; i < O_; ++i) {
    const float* wr = W_oh + (size_t)i * H_ + tid * 8;
    float s = 0.f;
#pragma unroll
    for (int u = 0; u < 8; ++u) s = fmaf(hv[u], wr[u], s);
    acc[i] = s;
  }
#pragma unroll
  for (int off = 32; off > 0; off >>= 1)
#pragma unroll
    for (int i = 0; i < O_; ++i) acc[i] += __shfl_down(acc[i], off);
  __shared__ float red[4][O_];
  if ((tid & 63) == 0)
#pragma unroll
    for (int i = 0; i < O_; ++i) red[tid >> 6][i] = acc[i];
  __syncthreads();
  if (tid == 0) {
    float o[O_], mx = -1e30f;
#pragma unroll
    for (int i = 0; i < O_; ++i) {
      o[i] = red[0][i] + red[1][i] + red[2][i] + red[3][i] + b_oh[i];
      mx = fmaxf(mx, o[i]);
    }
    float se = 0.f;
#pragma unroll
    for (int i = 0; i < O_; ++i) { o[i] = __expf(o[i] - mx); se += o[i]; }
    float inv = 1.f / se;
#pragma unroll
    for (int i = 0; i < O_; ++i) out[b * O_ + i] = o[i] * inv;
  }
}

extern "C" void kernel_launch(void* const* d_in, const int* in_sizes, int n_in,
                              void* d_out, int out_size, void* d_ws, size_t ws_size,
                              hipStream_t stream) {
  const int*   x     = (const int*)  d_in[0];
  const float* embed = (const float*)d_in[1];
  const float* W_hx  = (const float*)d_in[2];
  const float* b_hx  = (const float*)d_in[3];
  const float* W_hh  = (const float*)d_in[4];
  const float* b_hh  = (const float*)d_in[5];
  const float* W_oh  = (const float*)d_in[6];
  const float* b_oh  = (const float*)d_in[7];
  float* out = (float*)d_out;

  // workspace layout: Txh 80KB | Wb 8MB | Ha 4MB | Hb 4MB  (~16.1 MB)
  char* ws = (char*)d_ws;
  float* Txh = (float*)ws;
  u16* Wb = (u16*)(ws + (80 << 10));
  u16* Ha = (u16*)(ws + (80 << 10) + (8 << 20));
  u16* Hb = (u16*)(ws + (80 << 10) + (12 << 20));

  make_table<<<80, 256, 0, stream>>>(embed, W_hx, b_hx, Txh);
  conv_w<<<4096, 256, 0, stream>>>(W_hh, Wb);
  init_h0<<<8192, 256, 0, stream>>>(Txh, x, Ha);

  for (int t = 1; t < S_; ++t) {
    const u16* hin = (t & 1) ? Ha : Hb;
    u16* hout = (t & 1) ? Hb : Ha;
    rnn_step<<<512, 256, 0, stream>>>(hin, Wb, Txh, x, b_hh, hout, t);
  }
  // t=127 (odd) wrote Hb
  out_softmax<<<B_, 256, 0, stream>>>(Hb, W_oh, b_oh, out);
}